// Round 11
// baseline (62.858 us; speedup 1.0000x reference)
//
#include <hip/hip_runtime.h>
#include <cstdint>

#define TOK 2048
#define EMB 768
#define WIN 64
#define TCN (TOK / 16) // 128 token tiles (16-row)
#define DCN (EMB / 32) // 24 d-chunks (32-col)

typedef __attribute__((ext_vector_type(8))) __bf16 bf16x8;
typedef __attribute__((ext_vector_type(4))) float f32x4;

static __device__ __forceinline__ unsigned short f2bf(float f) {
  uint32_t x = __float_as_uint(f);
  uint32_t r = (x + 0x7fffu + ((x >> 16) & 1u)) >> 16;  // RNE
  return (unsigned short)r;
}

static __device__ __forceinline__ void gload_lds16(const void* g, void* l) {
  __builtin_amdgcn_global_load_lds(
      (const __attribute__((address_space(1))) uint32_t*)g,
      (__attribute__((address_space(3))) uint32_t*)l, 16, 0, 0);
}

// ---------------- prep: weights -> transposed bf16 WT[d][e] ----------------
__global__ __launch_bounds__(256) void prep_w(
    const float* __restrict__ Wk, const float* __restrict__ Wv,
    const float* __restrict__ Wq, unsigned short* __restrict__ WT) {
  __shared__ float t[32][33];
  const int bx = blockIdx.x, tid = threadIdx.x;
  const int wz = bx / 576, rem = bx - wz * 576;
  const float* w = (wz == 0) ? Wk : (wz == 1) ? Wv : Wq;
  const int d0 = (rem % 24) * 32, e0 = (rem / 24) * 32;
  const int tx = tid & 31, ty = tid >> 5;  // (32,8)
#pragma unroll
  for (int r = 0; r < 4; ++r)
    t[ty + r * 8][tx] = w[(size_t)(e0 + ty + r * 8) * EMB + d0 + tx];
  __syncthreads();
#pragma unroll
  for (int r = 0; r < 4; ++r) {
    const int dl = ty + r * 8, el = tx;
    WT[(size_t)wz * EMB * EMB + (size_t)(d0 + dl) * EMB + e0 + el] =
        f2bf(t[el][dl]);
  }
}

// ---------------- projections: bf16 MFMA GEMM ----------------
// C = A@W. A-fragments loaded DIRECTLY from fp32 inputs (no LDS, no prep
// pass): per af, 2x global_load_dwordx4 (128B-contiguous per 16-lane row
// group) + in-register cvt (v_cvt_pk_bf16_f32), hidden under MFMA. These
// loads depend only on kt -> compiler hoists them across barriers.
// B: gload_lds dbuf BK=64, T2 XOR involution swizzle (r10, proven).
// Epilogue writes MFMA-native layouts:
//   z=0 (k), z=2 (q): bf16 tiled [tok/16][d/32][16][32]
//   z=1 (v): bf16 V^T panels [tok/32][768][32]
__global__ __launch_bounds__(256) void proj_gemm(
    const float* __restrict__ key, const float* __restrict__ value,
    const float* __restrict__ query, const unsigned short* __restrict__ WT,
    unsigned short* __restrict__ k_t, unsigned short* __restrict__ vT_p,
    unsigned short* __restrict__ q_t) {
  const int z = blockIdx.z;
  const float* __restrict__ Af = (z == 0) ? key : (z == 1) ? value : query;
  const int bn0 = blockIdx.x * 128;  // output col (D)
  const int bm0 = blockIdx.y * 64;   // output row (token)
  const int tid = threadIdx.x, lane = tid & 63, w = tid >> 6;
  const int wr = w >> 1, wc = w & 1;
  const int l15 = lane & 15, l4 = lane >> 4;

  __shared__ unsigned short lB[2][128 * 64];  // 2 x 16KB

  const unsigned short* __restrict__ Bh = WT + (size_t)z * EMB * EMB;

  f32x4 acc[2][4] = {};

  // B staging: chunk ch covers rows ch*8..+8; source col pre-swizzled so
  // lds slot s holds global chunk s^(row&7) (T2 involution, rule #21).
  const int srow = lane >> 3;
  const int scol = ((lane & 7) ^ (srow & 7)) * 8;

  auto STAGE = [&](int b, int kt) {
    const int kk = kt * 64;
#pragma unroll
    for (int c = 0; c < 4; ++c) {
      const int ch = w * 4 + c;  // 16 B-chunks
      gload_lds16(Bh + (size_t)(bn0 + ch * 8 + srow) * EMB + kk + scol,
                  (char*)&lB[b][0] + ch * 1024);
    }
  };

  // A fragment base (fp32 direct): rows for m=0,1
  const float* __restrict__ a0p = Af + (size_t)(bm0 + wr * 32 + l15) * EMB + l4 * 8;
  const float* __restrict__ a1p = a0p + (size_t)16 * EMB;

  auto COMPUTE = [&](int b, int kt) {
#pragma unroll
    for (int ks = 0; ks < 2; ++ks) {
      const int kk = kt * 64 + ks * 32;
      bf16x8 af[2], bfr[4];
#pragma unroll
      for (int m = 0; m < 2; ++m) {
        const float* p = (m == 0 ? a0p : a1p) + kk;
        const float4 f0 = *(const float4*)p;
        const float4 f1 = *(const float4*)(p + 4);
        bf16x8 av;
        av[0] = (__bf16)f0.x; av[1] = (__bf16)f0.y;
        av[2] = (__bf16)f0.z; av[3] = (__bf16)f0.w;
        av[4] = (__bf16)f1.x; av[5] = (__bf16)f1.y;
        av[6] = (__bf16)f1.z; av[7] = (__bf16)f1.w;
        af[m] = av;
      }
#pragma unroll
      for (int n = 0; n < 4; ++n) {
        const int R = wc * 64 + n * 16 + l15;
        const int sl = (ks * 4 + l4) ^ (R & 7);
        bfr[n] = *(const bf16x8*)((const char*)&lB[b][0] + R * 128 + sl * 16);
      }
#pragma unroll
      for (int m = 0; m < 2; ++m)
#pragma unroll
        for (int n = 0; n < 4; ++n)
          acc[m][n] = __builtin_amdgcn_mfma_f32_16x16x32_bf16(af[m], bfr[n],
                                                              acc[m][n], 0, 0, 0);
    }
  };

  STAGE(0, 0);
  __syncthreads();  // prologue drain
#pragma unroll
  for (int kt = 0; kt < 12; kt += 2) {
    if (kt + 1 < 12) STAGE(1, kt + 1);
    COMPUTE(0, kt);
    __syncthreads();
    if (kt + 2 < 12) STAGE(0, kt + 2);
    COMPUTE(1, kt + 1);
    __syncthreads();
  }

  // ---- epilogue: write MFMA-native layouts ----
  if (z == 1) {
#pragma unroll
    for (int m = 0; m < 2; ++m) {
      const int tok0 = bm0 + wr * 32 + m * 16 + l4 * 4;
#pragma unroll
      for (int n = 0; n < 4; ++n) {
        const int d = bn0 + wc * 64 + n * 16 + l15;
        ushort4 pk;
        pk.x = f2bf(acc[m][n][0]); pk.y = f2bf(acc[m][n][1]);
        pk.z = f2bf(acc[m][n][2]); pk.w = f2bf(acc[m][n][3]);
        *(ushort4*)&vT_p[(((size_t)(tok0 >> 5) * EMB + d) << 5) + (tok0 & 31)] = pk;
      }
    }
  } else {
    unsigned short* __restrict__ dh = (z == 0) ? k_t : q_t;
#pragma unroll
    for (int m = 0; m < 2; ++m) {
      const int tok0 = bm0 + wr * 32 + m * 16 + l4 * 4;
#pragma unroll
      for (int n = 0; n < 4; ++n) {
        const int d = bn0 + wc * 64 + n * 16 + l15;
        const size_t base =
            (((size_t)(tok0 >> 4) * DCN + (d >> 5)) * 16) * 32 + (d & 31);
#pragma unroll
        for (int r = 0; r < 4; ++r)
          dh[base + (size_t)((tok0 & 15) + r) * 32] = f2bf(acc[m][n][r]);
      }
    }
  }
}

// ---------------- attn stage 1: scores -> exp -> P tiles + partial sums ----
// grid 512 = (qt 0..127) x (ksplit 0..3); 3 waves, wave owns N-tile
// nt = ks*3+w of 12. No max-subtraction (scores ~N(0,1), exp safe in fp32).
// P -> A-tile layout [qt*6+c][16 q][32 slot] bf16; partial sums -> Ssum.
__global__ __launch_bounds__(192) void attn_S(
    const unsigned short* __restrict__ k_t, const unsigned short* __restrict__ q_t,
    unsigned short* __restrict__ Pg, float* __restrict__ Ssum) {
  const int bid = ((int)blockIdx.x & 7) * 64 + ((int)blockIdx.x >> 3);  // XCD swz
  const int qt = bid >> 2, ks = bid & 3;
  const int lane = threadIdx.x & 63, w = threadIdx.x >> 6;  // 0..2
  const int nt = ks * 3 + w;                                // 0..11
  const int l15 = lane & 15, l4 = lane >> 4;
  const int t0 = qt * 16;
  const int js0 = (t0 - 64) & ~31;  // 32-aligned slot base (maybe <0)
  const int foff = l15 * 32 + l4 * 8;

  const size_t a_base = (size_t)qt * DCN * 512 + foff;
  const int ttile = min(max((js0 >> 4) + nt, 0), TCN - 1);  // clamp; masked
  const size_t b_base = (size_t)ttile * DCN * 512 + foff;

  f32x4 s = {};
#pragma unroll 8
  for (int kk = 0; kk < DCN; ++kk) {
    const bf16x8 ah = *(const bf16x8*)&q_t[a_base + (size_t)kk * 512];
    const bf16x8 bh = *(const bf16x8*)&k_t[b_base + (size_t)kk * 512];
    s = __builtin_amdgcn_mfma_f32_16x16x32_bf16(ah, bh, s, 0, 0, 0);
  }

  const float SC = 0.03608439182435161f;  // 768^-0.5
  const int j = js0 + nt * 16 + l15;
  const int qrow0 = t0 + l4 * 4;
  const int c = nt >> 1, colb = (nt & 1) * 16 + l15;

  float e[4];
#pragma unroll
  for (int r = 0; r < 4; ++r) {
    const int t = qrow0 + r;
    const bool ok = (j >= 0) && (j < TOK) && (j >= t - WIN) && (j <= t + WIN);
    e[r] = ok ? __expf(s[r] * SC) : 0.0f;
  }
#pragma unroll
  for (int r = 0; r < 4; ++r) {
    float sm = e[r];
#pragma unroll
    for (int off = 1; off < 16; off <<= 1) sm += __shfl_xor(sm, off);
    if (l15 == 0) Ssum[qt * 192 + nt * 16 + l4 * 4 + r] = sm;
  }
#pragma unroll
  for (int r = 0; r < 4; ++r)
    Pg[(((size_t)qt * 6 + c) * 16 + (l4 * 4 + r)) * 32 + colb] = f2bf(e[r]);
}

// ---------------- attn stage 2: PV + normalize ----------------
// grid 512 = (qt 0..127) x (dsplit 0..3); 3 waves, wave owns 64 d-cols.
// out[q][d] = (sum_k P[q][k] V[k][d]) / (rowsum * L).
__global__ __launch_bounds__(192) void attn_PV(
    const unsigned short* __restrict__ Pg, const float* __restrict__ Ssum,
    const unsigned short* __restrict__ vT_p, float* __restrict__ out) {
  const int bid = ((int)blockIdx.x & 7) * 64 + ((int)blockIdx.x >> 3);  // XCD swz
  const int qt = bid >> 2, ds = bid & 3;
  const int tid = threadIdx.x;
  const int lane = tid & 63, w = tid >> 6;
  const int l15 = lane & 15, l4 = lane >> 4;
  const int t0 = qt * 16;
  const int js0 = (t0 - 64) & ~31;

  __shared__ float ssum_l[192];
  __shared__ float rcp_l[16];

  ssum_l[tid] = Ssum[qt * 192 + tid];
  __syncthreads();
  if (tid < 16) {
    float s = 0.f;
#pragma unroll
    for (int i = 0; i < 12; ++i) s += ssum_l[i * 16 + tid];
    const int t = t0 + tid;
    const int len = min(TOK, t + WIN + 1) - max(0, t - WIN);
    rcp_l[tid] = 1.0f / (s * (float)len);
  }

  f32x4 o[4] = {};
  const int c0 = js0 >> 5;
#pragma unroll
  for (int kc = 0; kc < 6; ++kc) {
    const bf16x8 pa =
        *(const bf16x8*)&Pg[(((size_t)qt * 6 + kc) * 16 + l15) * 32 + l4 * 8];
    const int cc = min(max(c0 + kc, 0), TOK / 32 - 1);  // clamp; P=0 masks
    const size_t vb = (size_t)cc * (EMB * 32);
#pragma unroll
    for (int n = 0; n < 4; ++n) {
      const int d = ds * 192 + w * 64 + n * 16 + l15;
      const bf16x8 vbf = *(const bf16x8*)&vT_p[vb + (size_t)d * 32 + l4 * 8];
      o[n] = __builtin_amdgcn_mfma_f32_16x16x32_bf16(pa, vbf, o[n], 0, 0, 0);
    }
  }
  __syncthreads();  // rcp_l ready

  const int qrow0 = t0 + l4 * 4;
  float rr[4];
#pragma unroll
  for (int r = 0; r < 4; ++r) rr[r] = rcp_l[l4 * 4 + r];
#pragma unroll
  for (int n = 0; n < 4; ++n) {
    const int d = ds * 192 + w * 64 + n * 16 + l15;
#pragma unroll
    for (int r = 0; r < 4; ++r)
      out[(size_t)(qrow0 + r) * EMB + d] = o[n][r] * rr[r];
  }
}

extern "C" void kernel_launch(void* const* d_in, const int* in_sizes, int n_in,
                              void* d_out, int out_size, void* d_ws, size_t ws_size,
                              hipStream_t stream) {
  const float* key = (const float*)d_in[0];
  const float* value = (const float*)d_in[1];
  const float* query = (const float*)d_in[2];
  const float* Wk = (const float*)d_in[3];
  const float* Wv = (const float*)d_in[4];
  const float* Wq = (const float*)d_in[5];

  // ws layout (~14 MB): WT | k_t | q_t | vT_p | Pg | Ssum
  unsigned short* ws = (unsigned short*)d_ws;
  const size_t NW = (size_t)3 * EMB * EMB;
  const size_t NM = (size_t)TOK * EMB;
  unsigned short* WT = ws;
  unsigned short* k_t = WT + NW;
  unsigned short* q_t = k_t + NM;
  unsigned short* vT_p = q_t + NM;
  unsigned short* Pg = vT_p + NM;                           // 393216 u16
  float* Ssum = (float*)(Pg + (size_t)128 * 6 * 16 * 32);   // 24576 f32
  float* out = (float*)d_out;

  prep_w<<<1728, 256, 0, stream>>>(Wk, Wv, Wq, WT);
  proj_gemm<<<dim3(EMB / 128, TOK / 64, 3), 256, 0, stream>>>(
      key, value, query, WT, k_t, vT_p, q_t);
  attn_S<<<512, 192, 0, stream>>>(k_t, q_t, Pg, Ssum);
  attn_PV<<<512, 192, 0, stream>>>(Pg, Ssum, vT_p, out);
}

// Round 12
// 42.450 us; speedup vs baseline: 1.4807x; 1.4807x over previous
//
#include <hip/hip_runtime.h>
#include <cstdint>

#define TOK 2048
#define EMB 768
#define WIN 64
#define TCN (TOK / 16) // 128 token tiles (16-row)
#define DCN (EMB / 32) // 24 d-chunks (32-col)

typedef __attribute__((ext_vector_type(8))) __bf16 bf16x8;
typedef __attribute__((ext_vector_type(4))) float f32x4;

static __device__ __forceinline__ unsigned short f2bf(float f) {
  uint32_t x = __float_as_uint(f);
  uint32_t r = (x + 0x7fffu + ((x >> 16) & 1u)) >> 16;  // RNE
  return (unsigned short)r;
}

static __device__ __forceinline__ void gload_lds16(const void* g, void* l) {
  __builtin_amdgcn_global_load_lds(
      (const __attribute__((address_space(1))) uint32_t*)g,
      (__attribute__((address_space(3))) uint32_t*)l, 16, 0, 0);
}

// ---------------- prep (merged): z=0 inputs->bf16, z=1 weights->WT ---------
__global__ __launch_bounds__(256) void prep(
    const float* __restrict__ key, const float* __restrict__ value,
    const float* __restrict__ query, const float* __restrict__ Wk,
    const float* __restrict__ Wv, const float* __restrict__ Wq,
    unsigned short* __restrict__ Ab, unsigned short* __restrict__ WT) {
  __shared__ float t[32][33];
  const int z = blockIdx.z, bx = blockIdx.x, tid = threadIdx.x;
  if (z == 0) {
    const int64_t NE4 = (int64_t)TOK * EMB / 4;  // float4 per input
    const int64_t i = (int64_t)bx * 256 + tid;   // grid sized exactly 3*NE4
    const int which = (int)(i / NE4);
    const int64_t loc = i - (int64_t)which * NE4;
    const float4* src =
        (const float4*)(which == 0 ? key : which == 1 ? value : query);
    const float4 x = src[loc];
    ushort4 h;
    h.x = f2bf(x.x); h.y = f2bf(x.y); h.z = f2bf(x.z); h.w = f2bf(x.w);
    ((ushort4*)Ab)[i] = h;
  } else {
    if (bx >= 1728) return;
    const int wz = bx / 576, rem = bx - wz * 576;
    const float* w = (wz == 0) ? Wk : (wz == 1) ? Wv : Wq;
    const int d0 = (rem % 24) * 32, e0 = (rem / 24) * 32;
    const int tx = tid & 31, ty = tid >> 5;  // (32,8)
#pragma unroll
    for (int r = 0; r < 4; ++r)
      t[ty + r * 8][tx] = w[(size_t)(e0 + ty + r * 8) * EMB + d0 + tx];
    __syncthreads();
#pragma unroll
    for (int r = 0; r < 4; ++r) {
      const int dl = ty + r * 8, el = tx;
      WT[(size_t)wz * EMB * EMB + (size_t)(d0 + dl) * EMB + e0 + el] =
          f2bf(t[el][dl]);
    }
  }
}

// ---------------- projections: bf16 MFMA GEMM, BK=64, dbuf, BN=96 ----------
// C = A@W. T3-lite: STAGE(next) before COMPUTE(cur), one barrier per K-step.
// BN=96 -> grid 8x32x3 = 768 blocks = 3.00/CU (zero tail round).
// T2 XOR involution (slot ^ row&7) on staging source + fragment read.
// Epilogue writes MFMA-native layouts:
//   z=0 (k), z=2 (q): bf16 tiled [tok/16][d/32][16][32]
//   z=1 (v): bf16 V^T panels [tok/32][768][32]
__global__ __launch_bounds__(256) void proj_gemm(
    const unsigned short* __restrict__ Ab, const unsigned short* __restrict__ WT,
    unsigned short* __restrict__ k_t, unsigned short* __restrict__ vT_p,
    unsigned short* __restrict__ q_t) {
  const int z = blockIdx.z;
  const int bn0 = blockIdx.x * 96;   // output col (D)
  const int bm0 = blockIdx.y * 64;   // output row (token)
  const int tid = threadIdx.x, lane = tid & 63, w = tid >> 6;
  const int wr = w >> 1, wc = w & 1;
  const int l15 = lane & 15, l4 = lane >> 4;

  __shared__ unsigned short lA[2][64 * 64];   // 2 x 8KB
  __shared__ unsigned short lB[2][96 * 64];   // 2 x 12KB

  const unsigned short* __restrict__ Ah = Ab + (size_t)z * TOK * EMB;
  const unsigned short* __restrict__ Bh = WT + (size_t)z * EMB * EMB;

  f32x4 acc[2][3] = {};

  const int srow = lane >> 3;                       // row within chunk group
  const int scol = ((lane & 7) ^ (srow & 7)) * 8;   // bf16 col (16B chunks)

  auto STAGE = [&](int b, int kt) {
    const int kk = kt * 64;
#pragma unroll
    for (int c = 0; c < 2; ++c) {
      const int ch = w * 2 + c;  // 8 A-chunks (64 rows)
      gload_lds16(Ah + (size_t)(bm0 + ch * 8 + srow) * EMB + kk + scol,
                  (char*)&lA[b][0] + ch * 1024);
    }
#pragma unroll
    for (int c = 0; c < 3; ++c) {
      const int ch = w * 3 + c;  // 12 B-chunks (96 rows)
      gload_lds16(Bh + (size_t)(bn0 + ch * 8 + srow) * EMB + kk + scol,
                  (char*)&lB[b][0] + ch * 1024);
    }
  };

  auto COMPUTE = [&](int b) {
#pragma unroll
    for (int ks = 0; ks < 2; ++ks) {
      bf16x8 af[2], bfr[3];
#pragma unroll
      for (int m = 0; m < 2; ++m) {
        const int R = wr * 32 + m * 16 + l15;
        const int sl = (ks * 4 + l4) ^ (R & 7);
        af[m] = *(const bf16x8*)((const char*)&lA[b][0] + R * 128 + sl * 16);
      }
#pragma unroll
      for (int n = 0; n < 3; ++n) {
        const int R = wc * 48 + n * 16 + l15;
        const int sl = (ks * 4 + l4) ^ (R & 7);
        bfr[n] = *(const bf16x8*)((const char*)&lB[b][0] + R * 128 + sl * 16);
      }
#pragma unroll
      for (int m = 0; m < 2; ++m)
#pragma unroll
        for (int n = 0; n < 3; ++n)
          acc[m][n] = __builtin_amdgcn_mfma_f32_16x16x32_bf16(af[m], bfr[n],
                                                              acc[m][n], 0, 0, 0);
    }
  };

  STAGE(0, 0);
  __syncthreads();  // prologue drain
#pragma unroll
  for (int kt = 0; kt < 12; kt += 2) {
    if (kt + 1 < 12) STAGE(1, kt + 1);
    COMPUTE(0);
    __syncthreads();
    if (kt + 2 < 12) STAGE(0, kt + 2);
    COMPUTE(1);
    __syncthreads();
  }

  // ---- epilogue: write MFMA-native layouts ----
  if (z == 1) {
#pragma unroll
    for (int m = 0; m < 2; ++m) {
      const int tok0 = bm0 + wr * 32 + m * 16 + l4 * 4;
#pragma unroll
      for (int n = 0; n < 3; ++n) {
        const int d = bn0 + wc * 48 + n * 16 + l15;
        ushort4 pk;
        pk.x = f2bf(acc[m][n][0]); pk.y = f2bf(acc[m][n][1]);
        pk.z = f2bf(acc[m][n][2]); pk.w = f2bf(acc[m][n][3]);
        *(ushort4*)&vT_p[(((size_t)(tok0 >> 5) * EMB + d) << 5) + (tok0 & 31)] = pk;
      }
    }
  } else {
    unsigned short* __restrict__ dh = (z == 0) ? k_t : q_t;
#pragma unroll
    for (int m = 0; m < 2; ++m) {
      const int tok0 = bm0 + wr * 32 + m * 16 + l4 * 4;
#pragma unroll
      for (int n = 0; n < 3; ++n) {
        const int d = bn0 + wc * 48 + n * 16 + l15;
        const size_t base =
            (((size_t)(tok0 >> 4) * DCN + (d >> 5)) * 16) * 32 + (d & 31);
#pragma unroll
        for (int r = 0; r < 4; ++r)
          dh[base + (size_t)((tok0 & 15) + r) * 32] = f2bf(acc[m][n][r]);
      }
    }
  }
}

// ---------------- attn stage 1: scores -> exp -> P tiles + partial sums ----
// grid 512 = (qt 0..127) x (ksplit 0..3); 3 waves, wave owns N-tile
// nt = ks*3+w of 12. TWO independent MFMA accumulator chains (even/odd kk)
// for 2x chain ILP. No max-subtraction (scores ~N(0,1), exp safe in fp32).
// P -> A-tile layout [qt*6+c][16 q][32 slot] bf16; partial sums -> Ssum.
__global__ __launch_bounds__(192) void attn_S(
    const unsigned short* __restrict__ k_t, const unsigned short* __restrict__ q_t,
    unsigned short* __restrict__ Pg, float* __restrict__ Ssum) {
  const int bid = ((int)blockIdx.x & 7) * 64 + ((int)blockIdx.x >> 3);  // XCD swz
  const int qt = bid >> 2, ks = bid & 3;
  const int lane = threadIdx.x & 63, w = threadIdx.x >> 6;  // 0..2
  const int nt = ks * 3 + w;                                // 0..11
  const int l15 = lane & 15, l4 = lane >> 4;
  const int t0 = qt * 16;
  const int js0 = (t0 - 64) & ~31;  // 32-aligned slot base (maybe <0)
  const int foff = l15 * 32 + l4 * 8;

  const size_t a_base = (size_t)qt * DCN * 512 + foff;
  const int ttile = min(max((js0 >> 4) + nt, 0), TCN - 1);  // clamp; masked
  const size_t b_base = (size_t)ttile * DCN * 512 + foff;

  f32x4 s0 = {}, s1 = {};
#pragma unroll
  for (int kk = 0; kk < DCN; kk += 2) {
    const bf16x8 a0 = *(const bf16x8*)&q_t[a_base + (size_t)kk * 512];
    const bf16x8 b0 = *(const bf16x8*)&k_t[b_base + (size_t)kk * 512];
    const bf16x8 a1 = *(const bf16x8*)&q_t[a_base + (size_t)(kk + 1) * 512];
    const bf16x8 b1 = *(const bf16x8*)&k_t[b_base + (size_t)(kk + 1) * 512];
    s0 = __builtin_amdgcn_mfma_f32_16x16x32_bf16(a0, b0, s0, 0, 0, 0);
    s1 = __builtin_amdgcn_mfma_f32_16x16x32_bf16(a1, b1, s1, 0, 0, 0);
  }

  const float SC = 0.03608439182435161f;  // 768^-0.5
  const int j = js0 + nt * 16 + l15;
  const int qrow0 = t0 + l4 * 4;
  const int c = nt >> 1, colb = (nt & 1) * 16 + l15;

  float e[4];
#pragma unroll
  for (int r = 0; r < 4; ++r) {
    const int t = qrow0 + r;
    const bool ok = (j >= 0) && (j < TOK) && (j >= t - WIN) && (j <= t + WIN);
    e[r] = ok ? __expf((s0[r] + s1[r]) * SC) : 0.0f;
  }
#pragma unroll
  for (int r = 0; r < 4; ++r) {
    float sm = e[r];
#pragma unroll
    for (int off = 1; off < 16; off <<= 1) sm += __shfl_xor(sm, off);
    if (l15 == 0) Ssum[qt * 192 + nt * 16 + l4 * 4 + r] = sm;
  }
#pragma unroll
  for (int r = 0; r < 4; ++r)
    Pg[(((size_t)qt * 6 + c) * 16 + (l4 * 4 + r)) * 32 + colb] = f2bf(e[r]);
}

// ---------------- attn stage 2: PV + normalize ----------------
// grid 512 = (qt 0..127) x (dsplit 0..3); 3 waves, wave owns 64 d-cols.
// out[q][d] = (sum_k P[q][k] V[k][d]) / (rowsum * L).
__global__ __launch_bounds__(192) void attn_PV(
    const unsigned short* __restrict__ Pg, const float* __restrict__ Ssum,
    const unsigned short* __restrict__ vT_p, float* __restrict__ out) {
  const int bid = ((int)blockIdx.x & 7) * 64 + ((int)blockIdx.x >> 3);  // XCD swz
  const int qt = bid >> 2, ds = bid & 3;
  const int tid = threadIdx.x;
  const int lane = tid & 63, w = tid >> 6;
  const int l15 = lane & 15, l4 = lane >> 4;
  const int t0 = qt * 16;
  const int js0 = (t0 - 64) & ~31;

  __shared__ float ssum_l[192];
  __shared__ float rcp_l[16];

  ssum_l[tid] = Ssum[qt * 192 + tid];
  __syncthreads();
  if (tid < 16) {
    float s = 0.f;
#pragma unroll
    for (int i = 0; i < 12; ++i) s += ssum_l[i * 16 + tid];
    const int t = t0 + tid;
    const int len = min(TOK, t + WIN + 1) - max(0, t - WIN);
    rcp_l[tid] = 1.0f / (s * (float)len);
  }

  f32x4 o[4] = {};
  const int c0 = js0 >> 5;
#pragma unroll
  for (int kc = 0; kc < 6; ++kc) {
    const bf16x8 pa =
        *(const bf16x8*)&Pg[(((size_t)qt * 6 + kc) * 16 + l15) * 32 + l4 * 8];
    const int cc = min(max(c0 + kc, 0), TOK / 32 - 1);  // clamp; P=0 masks
    const size_t vb = (size_t)cc * (EMB * 32);
#pragma unroll
    for (int n = 0; n < 4; ++n) {
      const int d = ds * 192 + w * 64 + n * 16 + l15;
      const bf16x8 vbf = *(const bf16x8*)&vT_p[vb + (size_t)d * 32 + l4 * 8];
      o[n] = __builtin_amdgcn_mfma_f32_16x16x32_bf16(pa, vbf, o[n], 0, 0, 0);
    }
  }
  __syncthreads();  // rcp_l ready

  const int qrow0 = t0 + l4 * 4;
  float rr[4];
#pragma unroll
  for (int r = 0; r < 4; ++r) rr[r] = rcp_l[l4 * 4 + r];
#pragma unroll
  for (int n = 0; n < 4; ++n) {
    const int d = ds * 192 + w * 64 + n * 16 + l15;
#pragma unroll
    for (int r = 0; r < 4; ++r)
      out[(size_t)(qrow0 + r) * EMB + d] = o[n][r] * rr[r];
  }
}

extern "C" void kernel_launch(void* const* d_in, const int* in_sizes, int n_in,
                              void* d_out, int out_size, void* d_ws, size_t ws_size,
                              hipStream_t stream) {
  const float* key = (const float*)d_in[0];
  const float* value = (const float*)d_in[1];
  const float* query = (const float*)d_in[2];
  const float* Wk = (const float*)d_in[3];
  const float* Wv = (const float*)d_in[4];
  const float* Wq = (const float*)d_in[5];

  // ws layout (~25 MB): Ab | WT | k_t | q_t | vT_p | Pg | Ssum
  unsigned short* ws = (unsigned short*)d_ws;
  const size_t NA = (size_t)3 * TOK * EMB;
  const size_t NW = (size_t)3 * EMB * EMB;
  const size_t NM = (size_t)TOK * EMB;
  unsigned short* Ab = ws;
  unsigned short* WT = Ab + NA;
  unsigned short* k_t = WT + NW;
  unsigned short* q_t = k_t + NM;
  unsigned short* vT_p = q_t + NM;
  unsigned short* Pg = vT_p + NM;                           // 393216 u16
  float* Ssum = (float*)(Pg + (size_t)128 * 6 * 16 * 32);   // 24576 f32
  float* out = (float*)d_out;

  prep<<<dim3(3 * TOK * EMB / 4 / 256, 1, 2), 256, 0, stream>>>(
      key, value, query, Wk, Wv, Wq, Ab, WT);
  proj_gemm<<<dim3(EMB / 96, TOK / 64, 3), 256, 0, stream>>>(
      Ab, WT, k_t, vT_p, q_t);
  attn_S<<<512, 192, 0, stream>>>(k_t, q_t, Pg, Ssum);
  attn_PV<<<512, 192, 0, stream>>>(Pg, Ssum, vT_p, out);
}